// Round 10
// baseline (84.000 us; speedup 1.0000x reference)
//
#include <hip/hip_runtime.h>
#include <hip/hip_bf16.h>
#include <cstdint>

#define MAX_NORM (1.0f - 1e-5f)
#define LN2 0.69314718056f
// w-clamp equivalent of norm <= MAX_NORM: w_max = (1+MAX_NORM)/(1-MAX_NORM)
#define WMAX ((1.0f + MAX_NORM) / (1.0f - MAX_NORM))

typedef __attribute__((ext_vector_type(8))) short bf16x8;
typedef __attribute__((ext_vector_type(4))) float f32x4;

__device__ __forceinline__ unsigned short f2bf(float f) {
  union { float f; unsigned int u; } c; c.f = f;
  unsigned int r = c.u + 0x7fffu + ((c.u >> 16) & 1u);
  return (unsigned short)(r >> 16);
}

// Fused prep: one wave per row, rows [0,M) are x, rows [M,M+N) are protos.
// x:      bf16-cast; x2 = ||x||^2; fx = 2/(1-x2)
// protos: expmap0+project -> bf16; gy = 1/(1-y2); hy = gy*y2; es2 = -exp(ls)*ln2
__global__ void prep_all(const float* __restrict__ x, const float* __restrict__ pt,
                         const float* __restrict__ ls,
                         unsigned short* __restrict__ xbf, unsigned short* __restrict__ pbf,
                         float* __restrict__ x2, float* __restrict__ fx,
                         float* __restrict__ gy, float* __restrict__ hy,
                         float* __restrict__ es2, int M, int N, int D) {
  int row = blockIdx.x * (blockDim.x >> 6) + (threadIdx.x >> 6);
  int lane = threadIdx.x & 63;
  if (row >= M + N) return;
  const bool isX = row < M;
  const int r = isX ? row : row - M;
  const float* src = (isX ? x : pt) + (size_t)r * D;
  f32x4 v = ((const f32x4*)src)[lane];
  float ss = v[0]*v[0] + v[1]*v[1] + v[2]*v[2] + v[3]*v[3];
  #pragma unroll
  for (int off = 32; off >= 1; off >>= 1) ss += __shfl_xor(ss, off);
  float scale = 1.0f;
  float outsq = ss;
  if (!isX) {
    float vn  = sqrtf(ss);
    float vnc = fmaxf(vn, 1e-15f);
    float th  = tanhf(vnc);
    scale = th / vnc;                 // p = scale * v
    float pn = scale * vn;            // ||p||
    if (pn > MAX_NORM) { float pr = MAX_NORM / pn; scale *= pr; pn = MAX_NORM; }
    outsq = pn * pn;
  }
  unsigned short* dst = (isX ? xbf : pbf) + (size_t)r * D + lane * 4;
  unsigned long long pk =
        (unsigned long long)f2bf(v[0]*scale)
      | ((unsigned long long)f2bf(v[1]*scale) << 16)
      | ((unsigned long long)f2bf(v[2]*scale) << 32)
      | ((unsigned long long)f2bf(v[3]*scale) << 48);
  *(unsigned long long*)dst = pk;
  if (lane == 0) {
    if (isX) {
      x2[r] = outsq;
      fx[r] = 2.0f / (1.0f - outsq);
    } else {
      float g = 1.0f / (1.0f - outsq);
      gy[r]  = g;
      hy[r]  = g * outsq;
      es2[r] = -__expf(ls[r]) * LN2;
    }
  }
}

// NO-LDS gemm: inputs (2 MB + 4 MB bf16) are L2/L3-resident after prep, so
// MFMA fragments are loaded DIRECTLY from global (16 rows x 64 B sectors per
// load instr). No __shared__, no barriers, no staging -> every wave is an
// independent async load->MFMA stream; unrolled K-loop lets the compiler
// software-pipeline. 128x128 tile, 4 waves (2x2), 4x4 frags of 16x16x32.
// Swapped operands (mfma(B=proto, A=x)): C/D col=lane&15 -> M rows, regs ->
// 4 consecutive N cols -> f32x4 stores (R6/R7-refchecked layout).
__global__ __launch_bounds__(256, 3)
void hyp_gemm(const unsigned short* __restrict__ xbf,
              const unsigned short* __restrict__ pbf,
              const float* __restrict__ x2, const float* __restrict__ fx,
              const float* __restrict__ gy, const float* __restrict__ hy,
              const float* __restrict__ es2, float* __restrict__ out,
              int M, int N, int K) {
  const int t    = threadIdx.x;
  const int wv   = t >> 6;
  const int lane = t & 63;
  const int wr   = wv >> 1, wc = wv & 1;
  const int frow = lane & 15, kgrp = lane >> 4;
  const int nTM  = M >> 7;
  const int tileM = blockIdx.x % nTM;
  const int tileN = blockIdx.x / nTM;
  const int gr0 = tileM * 128 + wr * 64;
  const int gc0 = tileN * 128 + wc * 64;

  f32x4 acc[4][4];
  #pragma unroll
  for (int m = 0; m < 4; ++m)
    #pragma unroll
    for (int n = 0; n < 4; ++n) acc[m][n] = (f32x4){0.f, 0.f, 0.f, 0.f};

  // per-lane fragment row pointers (16 B each at k-offset kgrp*8)
  const unsigned short* pA[4];
  const unsigned short* pB[4];
  #pragma unroll
  for (int m = 0; m < 4; ++m)
    pA[m] = xbf + (size_t)(gr0 + m * 16 + frow) * K + kgrp * 8;
  #pragma unroll
  for (int n = 0; n < 4; ++n)
    pB[n] = pbf + (size_t)(gc0 + n * 16 + frow) * K + kgrp * 8;

  #pragma unroll
  for (int k0 = 0; k0 < 256; k0 += 32) {   // K == 256
    bf16x8 af[4], bg[4];
    #pragma unroll
    for (int m = 0; m < 4; ++m) af[m] = *(const bf16x8*)(pA[m] + k0);
    #pragma unroll
    for (int n = 0; n < 4; ++n) bg[n] = *(const bf16x8*)(pB[n] + k0);
    #pragma unroll
    for (int m = 0; m < 4; ++m)
      #pragma unroll
      for (int n = 0; n < 4; ++n)
        acc[m][n] = __builtin_amdgcn_mfma_f32_16x16x32_bf16(bg[n], af[m], acc[m][n], 0, 0, 0);
  }

  // Epilogue (R7): out[(gr0+m*16+frow)*N + gc0+n*16+kgrp*4+r]
  // u = 1 + fx*(gy*(x2-2xy) + hy); w = u + sqrt(u^2-1); out = es2*log2(w)
  float x2s[4], fxs[4];
  #pragma unroll
  for (int m = 0; m < 4; ++m) {
    x2s[m] = x2[gr0 + m * 16 + frow];
    fxs[m] = fx[gr0 + m * 16 + frow];
  }
  #pragma unroll
  for (int n = 0; n < 4; ++n) {
    const int c0 = gc0 + n * 16 + kgrp * 4;
    f32x4 gv = *(const f32x4*)(gy  + c0);
    f32x4 hv = *(const f32x4*)(hy  + c0);
    f32x4 ev = *(const f32x4*)(es2 + c0);
    #pragma unroll
    for (int m = 0; m < 4; ++m) {
      f32x4 a4 = acc[m][n];
      f32x4 o;
      #pragma unroll
      for (int r = 0; r < 4; ++r) {
        float xy = a4[r];
        float u  = fmaf(fxs[m], fmaf(gv[r], fmaf(-2.0f, xy, x2s[m]), hv[r]), 1.0f);
        float t2 = fmaxf(fmaf(u, u, -1.0f), 0.0f);
        float w  = u + __builtin_amdgcn_sqrtf(t2);
        w = fminf(w, WMAX);
        o[r] = ev[r] * __log2f(w);
      }
      *(f32x4*)&out[(size_t)(gr0 + m * 16 + frow) * N + c0] = o;
    }
  }
}

extern "C" void kernel_launch(void* const* d_in, const int* in_sizes, int n_in,
                              void* d_out, int out_size, void* d_ws, size_t ws_size,
                              hipStream_t stream) {
  const float* x  = (const float*)d_in[0];
  const float* pt = (const float*)d_in[1];
  const float* ls = (const float*)d_in[2];
  const int Csz = in_sizes[2];
  const int D   = in_sizes[1] / Csz;   // 256
  const int Bsz = in_sizes[0] / D;     // 4096
  const int M = Bsz, N = Csz, K = D;
  float* outp = (float*)d_out;

  char* ws = (char*)d_ws;
  unsigned short* xbf = (unsigned short*)ws; ws += (size_t)M * K * 2;
  unsigned short* pbf = (unsigned short*)ws; ws += (size_t)N * K * 2;
  float* x2  = (float*)ws; ws += (size_t)M * 4;
  float* fx  = (float*)ws; ws += (size_t)M * 4;
  float* gy  = (float*)ws; ws += (size_t)N * 4;
  float* hy  = (float*)ws; ws += (size_t)N * 4;
  float* es2 = (float*)ws; ws += (size_t)N * 4;

  hipLaunchKernelGGL(prep_all, dim3((M + N + 3) / 4), dim3(256), 0, stream,
                     x, pt, ls, xbf, pbf, x2, fx, gy, hy, es2, M, N, K);
  hipLaunchKernelGGL(hyp_gemm, dim3((M / 128) * (N / 128)), dim3(256), 0, stream,
                     xbf, pbf, x2, fx, gy, hy, es2, outp, M, N, K);
}

// Round 11
// 53.149 us; speedup vs baseline: 1.5805x; 1.5805x over previous
//
#include <hip/hip_runtime.h>
#include <hip/hip_bf16.h>
#include <cstdint>

#define MAX_NORM (1.0f - 1e-5f)
#define LN2 0.69314718056f
// w-clamp equivalent of norm <= MAX_NORM: w_max = (1+MAX_NORM)/(1-MAX_NORM)
#define WMAX ((1.0f + MAX_NORM) / (1.0f - MAX_NORM))

typedef __attribute__((ext_vector_type(8))) short bf16x8;
typedef __attribute__((ext_vector_type(4))) float f32x4;

__device__ __forceinline__ unsigned short f2bf(float f) {
  union { float f; unsigned int u; } c; c.f = f;
  unsigned int r = c.u + 0x7fffu + ((c.u >> 16) & 1u);
  return (unsigned short)(r >> 16);
}

__device__ __forceinline__ void gld16(const unsigned short* g, unsigned short* l) {
  __builtin_amdgcn_global_load_lds(
      (const __attribute__((address_space(1))) unsigned int*)g,
      (__attribute__((address_space(3))) unsigned int*)l, 16, 0, 0);
}

// Fused prep: one wave per row, rows [0,M) are x, rows [M,M+N) are protos.
// x:      bf16-cast; x2 = ||x||^2; fx = 2/(1-x2)
// protos: expmap0+project -> bf16; gy = 1/(1-y2); hy = gy*y2; es2 = -exp(ls)*ln2
__global__ void prep_all(const float* __restrict__ x, const float* __restrict__ pt,
                         const float* __restrict__ ls,
                         unsigned short* __restrict__ xbf, unsigned short* __restrict__ pbf,
                         float* __restrict__ x2, float* __restrict__ fx,
                         float* __restrict__ gy, float* __restrict__ hy,
                         float* __restrict__ es2, int M, int N, int D) {
  int row = blockIdx.x * (blockDim.x >> 6) + (threadIdx.x >> 6);
  int lane = threadIdx.x & 63;
  if (row >= M + N) return;
  const bool isX = row < M;
  const int r = isX ? row : row - M;
  const float* src = (isX ? x : pt) + (size_t)r * D;
  f32x4 v = ((const f32x4*)src)[lane];
  float ss = v[0]*v[0] + v[1]*v[1] + v[2]*v[2] + v[3]*v[3];
  #pragma unroll
  for (int off = 32; off >= 1; off >>= 1) ss += __shfl_xor(ss, off);
  float scale = 1.0f;
  float outsq = ss;
  if (!isX) {
    float vn  = sqrtf(ss);
    float vnc = fmaxf(vn, 1e-15f);
    float th  = tanhf(vnc);
    scale = th / vnc;                 // p = scale * v
    float pn = scale * vn;            // ||p||
    if (pn > MAX_NORM) { float pr = MAX_NORM / pn; scale *= pr; pn = MAX_NORM; }
    outsq = pn * pn;
  }
  unsigned short* dst = (isX ? xbf : pbf) + (size_t)r * D + lane * 4;
  unsigned long long pk =
        (unsigned long long)f2bf(v[0]*scale)
      | ((unsigned long long)f2bf(v[1]*scale) << 16)
      | ((unsigned long long)f2bf(v[2]*scale) << 32)
      | ((unsigned long long)f2bf(v[3]*scale) << 48);
  *(unsigned long long*)dst = pk;
  if (lane == 0) {
    if (isX) {
      x2[r] = outsq;
      fx[r] = 2.0f / (1.0f - outsq);
    } else {
      float g = 1.0f / (1.0f - outsq);
      gy[r]  = g;
      hy[r]  = g * outsq;
      es2[r] = -__expf(ls[r]) * LN2;
    }
  }
}

// 128x128 sub-tile core (R6/R7-proven: BK=64 dbuf, __syncthreads, plain f32x4
// stores, swapped-operand MFMA). NEW: 4 N-adjacent sub-tiles per block with
// SOFTWARE-PIPELINED EPILOGUE: while sub-tile t's K-loop runs, sub-tile t-1's
// epilogue executes in 4 slices (one n-quarter per K-iter), so VALU/trans/
// stores overlap the staging windows and stores flow continuously.
// accA/accB ping-pong (macro-static indices, no runtime acc indexing).
__global__ __launch_bounds__(256, 2)
void hyp_gemm(const unsigned short* __restrict__ xbf,
              const unsigned short* __restrict__ pbf,
              const float* __restrict__ x2, const float* __restrict__ fx,
              const float* __restrict__ gy, const float* __restrict__ hy,
              const float* __restrict__ es2, float* __restrict__ out,
              int M, int N, int K) {
  __shared__ __align__(16) unsigned short As[2][2][128 * 32];
  __shared__ __align__(16) unsigned short Bs[2][2][128 * 32];
  const int t    = threadIdx.x;
  const int wv   = t >> 6;
  const int lane = t & 63;
  const int wr   = wv >> 1, wc = wv & 1;
  const int frow = lane & 15, kgrp = lane >> 4;
  const int nTM  = M >> 7;
  const int tileM  = blockIdx.x % nTM;
  const int tileN0 = (blockIdx.x / nTM) * 4;    // four 128-wide N sub-tiles
  const int gr0 = tileM * 128 + wr * 64;

  f32x4 accA[4][4], accB[4][4];

  // staging: per plane (32 k-elems), per j (64-row half): wave wv covers rows
  // j*64 + wv*16 + (lane>>2), k-elems (lane&3)*8 .. +8  (16 B per lane)
  const int srow  = wv * 16 + (lane >> 2);
  const int skoff = (lane & 3) * 8;
  const unsigned short* gA  = xbf + (size_t)(tileM * 128 + srow) * K + skoff;
  const unsigned short* gB0 = pbf + (size_t)(tileN0 * 128 + srow) * K + skoff;
  const size_t rskip = (size_t)64 * K;    // 64-row half advance
  const size_t nskip = (size_t)128 * K;   // sub-tile (128-row) advance

  // epilogue per-M-row scalars, shared by all 4 sub-tiles
  float x2s[4], fxs[4];
  #pragma unroll
  for (int m = 0; m < 4; ++m) {
    x2s[m] = x2[gr0 + m * 16 + frow];
    fxs[m] = fx[gr0 + m * 16 + frow];
  }

#define STAGE(b, kt, GBP)                                                      \
  {                                                                            \
    _Pragma("unroll")                                                          \
    for (int p = 0; p < 2; ++p) {                                              \
      _Pragma("unroll")                                                        \
      for (int j = 0; j < 2; ++j) {                                            \
        gld16(gA + (size_t)j * rskip + (kt) * 64 + p * 32,                     \
              &As[b][p][(j * 64 + wv * 16) * 32]);                             \
        gld16((GBP) + (size_t)j * rskip + (kt) * 64 + p * 32,                  \
              &Bs[b][p][(j * 64 + wv * 16) * 32]);                             \
      }                                                                        \
    }                                                                          \
  }

#define COMPUTE(b, ACC)                                                        \
  {                                                                            \
    _Pragma("unroll")                                                          \
    for (int p = 0; p < 2; ++p) {                                              \
      bf16x8 af[4], bg[4];                                                     \
      _Pragma("unroll")                                                        \
      for (int m = 0; m < 4; ++m)                                              \
        af[m] = *(const bf16x8*)&As[b][p][(wr * 64 + m * 16 + frow) * 32 + kgrp * 8]; \
      _Pragma("unroll")                                                        \
      for (int n = 0; n < 4; ++n)                                              \
        bg[n] = *(const bf16x8*)&Bs[b][p][(wc * 64 + n * 16 + frow) * 32 + kgrp * 8]; \
      _Pragma("unroll")                                                        \
      for (int m = 0; m < 4; ++m)                                              \
        _Pragma("unroll")                                                      \
        for (int n = 0; n < 4; ++n)                                            \
          ACC[m][n] = __builtin_amdgcn_mfma_f32_16x16x32_bf16(bg[n], af[m], ACC[m][n], 0, 0, 0); \
    }                                                                          \
  }

  // one n-quarter of a finished sub-tile's epilogue (static NN = K-iter index)
  // u = 1 + fx*(gy*(x2-2xy) + hy); w = u + sqrt(u^2-1); out = es2*log2(w)
#define EPI_SLICE(ACC, TNP, NN)                                                \
  {                                                                            \
    const int c0 = (tileN0 + (TNP)) * 128 + wc * 64 + (NN) * 16 + kgrp * 4;    \
    f32x4 gv = *(const f32x4*)(gy  + c0);                                      \
    f32x4 hv = *(const f32x4*)(hy  + c0);                                      \
    f32x4 ev = *(const f32x4*)(es2 + c0);                                      \
    _Pragma("unroll")                                                          \
    for (int m = 0; m < 4; ++m) {                                              \
      f32x4 a4 = ACC[m][(NN)];                                                 \
      f32x4 o;                                                                 \
      _Pragma("unroll")                                                        \
      for (int r = 0; r < 4; ++r) {                                            \
        float xy = a4[r];                                                      \
        float u  = fmaf(fxs[m], fmaf(gv[r], fmaf(-2.0f, xy, x2s[m]), hv[r]), 1.0f); \
        float t2 = fmaxf(fmaf(u, u, -1.0f), 0.0f);                             \
        float w  = fminf(u + __builtin_amdgcn_sqrtf(t2), WMAX);                \
        o[r] = ev[r] * __log2f(w);                                             \
      }                                                                        \
      *(f32x4*)&out[(size_t)(gr0 + m * 16 + frow) * N + c0] = o;               \
    }                                                                          \
  }

  // Pipeline: tile TN's K-loop carries tile TN-1's epilogue slices; tile
  // TN+1's first buffer is staged during TN's last K-iter (no bubble).
  // cur starts each tile at 0 (4 toggles/tile).
#define TILE(TN, ACCC, ACCP)                                                   \
  {                                                                            \
    _Pragma("unroll")                                                          \
    for (int m = 0; m < 4; ++m)                                                \
      _Pragma("unroll")                                                        \
      for (int n = 0; n < 4; ++n) ACCC[m][n] = (f32x4){0.f, 0.f, 0.f, 0.f};    \
    __syncthreads();                                                           \
    _Pragma("unroll")                                                          \
    for (int kt = 0; kt < 4; ++kt) {                                           \
      if (kt < 3)          STAGE(cur ^ 1, kt + 1, gB0 + (TN) * nskip)          \
      else if ((TN) < 3)   STAGE(cur ^ 1, 0, gB0 + ((TN) + 1) * nskip)         \
      if ((TN) > 0)        EPI_SLICE(ACCP, (TN) - 1, kt)                       \
      COMPUTE(cur, ACCC)                                                       \
      __syncthreads();                                                         \
      cur ^= 1;                                                                \
    }                                                                          \
  }

  STAGE(0, 0, gB0)
  int cur = 0;
  TILE(0, accA, accB)
  TILE(1, accB, accA)
  TILE(2, accA, accB)
  TILE(3, accB, accA)
  // drain: tile3's epilogue
  #pragma unroll
  for (int n = 0; n < 4; ++n) EPI_SLICE(accB, 3, n)

#undef TILE
#undef EPI_SLICE
#undef COMPUTE
#undef STAGE
}

extern "C" void kernel_launch(void* const* d_in, const int* in_sizes, int n_in,
                              void* d_out, int out_size, void* d_ws, size_t ws_size,
                              hipStream_t stream) {
  const float* x  = (const float*)d_in[0];
  const float* pt = (const float*)d_in[1];
  const float* ls = (const float*)d_in[2];
  const int Csz = in_sizes[2];
  const int D   = in_sizes[1] / Csz;   // 256
  const int Bsz = in_sizes[0] / D;     // 4096
  const int M = Bsz, N = Csz, K = D;
  float* outp = (float*)d_out;

  char* ws = (char*)d_ws;
  unsigned short* xbf = (unsigned short*)ws; ws += (size_t)M * K * 2;
  unsigned short* pbf = (unsigned short*)ws; ws += (size_t)N * K * 2;
  float* x2  = (float*)ws; ws += (size_t)M * 4;
  float* fx  = (float*)ws; ws += (size_t)M * 4;
  float* gy  = (float*)ws; ws += (size_t)N * 4;
  float* hy  = (float*)ws; ws += (size_t)N * 4;
  float* es2 = (float*)ws; ws += (size_t)N * 4;

  hipLaunchKernelGGL(prep_all, dim3((M + N + 3) / 4), dim3(256), 0, stream,
                     x, pt, ls, xbf, pbf, x2, fx, gy, hy, es2, M, N, K);
  hipLaunchKernelGGL(hyp_gemm, dim3((M / 128) * (N / 512)), dim3(256), 0, stream,
                     xbf, pbf, x2, fx, gy, hy, es2, outp, M, N, K);
}